// Round 5
// baseline (301.586 us; speedup 1.0000x reference)
//
#include <hip/hip_runtime.h>
#include <hip/hip_bf16.h>

#define N_NODES 50000
#define N_EDGES 312500
#define WIDTH   256
#define LN_EPS  1e-5f

typedef __attribute__((ext_vector_type(8))) short bf16x8;
typedef __attribute__((ext_vector_type(4))) float f32x4;

__device__ __forceinline__ float bf_lo(unsigned u) { return __uint_as_float(u << 16); }
__device__ __forceinline__ float bf_hi(unsigned u) { return __uint_as_float(u & 0xffff0000u); }

// ---------------------------------------------------------------------------
// CSR build: count -> single-block scan -> fill (packed with dinv[src])
// ---------------------------------------------------------------------------
__global__ void count_dst(const int* __restrict__ dst, int* __restrict__ counts, int e) {
    int i = blockIdx.x * blockDim.x + threadIdx.x;
    if (i < e) atomicAdd(&counts[dst[i]], 1);
}

// Single-block exclusive scan over 50000 counts; writes offsets, cursor
// (reuses counts), and dinv = rsqrt(count+1). 1024 thr x 49 elems.
#define SCAN_CHUNK 49
__global__ __launch_bounds__(1024) void scan_all(int* __restrict__ counts,
                                                 int* __restrict__ offsets,
                                                 float* __restrict__ dinv) {
    const int t    = threadIdx.x;
    const int lane = t & 63;
    const int w    = t >> 6;            // 16 waves
    const int base = t * SCAN_CHUNK;

    int local[SCAN_CHUNK];
    int sum = 0;
    #pragma unroll
    for (int i = 0; i < SCAN_CHUNK; i++) {
        int idx = base + i;
        int v = (idx < N_NODES) ? counts[idx] : 0;
        local[i] = v;
        sum += v;
    }
    // wave inclusive scan of per-thread sums
    int inc = sum;
    #pragma unroll
    for (int off = 1; off < 64; off <<= 1) {
        int u = __shfl_up(inc, off, 64);
        if (lane >= off) inc += u;
    }
    __shared__ int wsum[16];
    if (lane == 63) wsum[w] = inc;
    __syncthreads();
    int woff = 0;
    #pragma unroll
    for (int k = 0; k < 16; k++) if (k < w) woff += wsum[k];

    int run = woff + inc - sum;         // exclusive prefix for this thread
    #pragma unroll
    for (int i = 0; i < SCAN_CHUNK; i++) {
        int idx = base + i;
        if (idx < N_NODES) {
            offsets[idx] = run;
            counts[idx]  = run;                          // cursor
            dinv[idx]    = rsqrtf((float)(local[i] + 1)); // +1 self-loop
        }
        run += local[i];
    }
    if (t == 1023) offsets[N_NODES] = N_EDGES;
}

// csr2[pos] = {src, bits(dinv[src])} -- kills the dependent dinv gather later
__global__ void fill_csr(const int* __restrict__ src, const int* __restrict__ dst,
                         const float* __restrict__ dinv,
                         int* __restrict__ cursor, int2* __restrict__ csr2, int e) {
    int i = blockIdx.x * blockDim.x + threadIdx.x;
    if (i < e) {
        int s = src[i];
        int pos = atomicAdd(&cursor[dst[i]], 1);
        csr2[pos] = make_int2(s, __float_as_int(dinv[s]));
    }
}

// ---------------------------------------------------------------------------
// MFMA GEMM with fused fp32->bf16 conversion in staging.
// h[m][nc] = sum_k x[m][k] * W[nc][k]; block 256 thr = 4 waves (2x2),
// tile 128x128, BK=64, K=256. LDS rows padded to 72 shorts.
// ---------------------------------------------------------------------------
__global__ __launch_bounds__(256) void gemm_mfma(const float* __restrict__ x,
                                                 const float* __restrict__ W,
                                                 __hip_bfloat16* __restrict__ h) {
    __shared__ short As[128][72];
    __shared__ short Bs[128][72];
    const int t    = threadIdx.x;
    const int lane = t & 63;
    const int wv   = t >> 6;
    const int wm   = wv & 1;
    const int wn   = wv >> 1;
    const int lrow = lane & 15;
    const int quad = lane >> 4;
    const int mrow0 = blockIdx.x * 128;
    const int ncol0 = blockIdx.y * 128;

    f32x4 acc[4][4];
    #pragma unroll
    for (int i = 0; i < 4; i++)
        #pragma unroll
        for (int j = 0; j < 4; j++)
            #pragma unroll
            for (int r = 0; r < 4; r++) acc[i][j][r] = 0.0f;

    const int sr = t >> 3;            // 0..31
    const int sg = t & 7;             // 0..7

    for (int kc = 0; kc < 4; kc++) {
        int k0 = kc * 64;
        if (kc) __syncthreads();
        #pragma unroll
        for (int p = 0; p < 4; p++) {
            int r  = p * 32 + sr;
            int gr = mrow0 + r;
            union { __hip_bfloat16 hh[8]; bf16x8 v; } ua;
            if (gr < N_NODES) {
                const float* xp = x + (size_t)gr * WIDTH + k0 + sg * 8;
                float4 f0 = *(const float4*)xp;
                float4 f1 = *(const float4*)(xp + 4);
                ua.hh[0] = __float2bfloat16(f0.x); ua.hh[1] = __float2bfloat16(f0.y);
                ua.hh[2] = __float2bfloat16(f0.z); ua.hh[3] = __float2bfloat16(f0.w);
                ua.hh[4] = __float2bfloat16(f1.x); ua.hh[5] = __float2bfloat16(f1.y);
                ua.hh[6] = __float2bfloat16(f1.z); ua.hh[7] = __float2bfloat16(f1.w);
            } else {
                ua.v = (bf16x8){0,0,0,0,0,0,0,0};
            }
            *(bf16x8*)&As[r][sg * 8] = ua.v;

            int gn = ncol0 + r;       // always < 256
            const float* wp = W + (size_t)gn * WIDTH + k0 + sg * 8;
            float4 g0 = *(const float4*)wp;
            float4 g1 = *(const float4*)(wp + 4);
            union { __hip_bfloat16 hh[8]; bf16x8 v; } ub;
            ub.hh[0] = __float2bfloat16(g0.x); ub.hh[1] = __float2bfloat16(g0.y);
            ub.hh[2] = __float2bfloat16(g0.z); ub.hh[3] = __float2bfloat16(g0.w);
            ub.hh[4] = __float2bfloat16(g1.x); ub.hh[5] = __float2bfloat16(g1.y);
            ub.hh[6] = __float2bfloat16(g1.z); ub.hh[7] = __float2bfloat16(g1.w);
            *(bf16x8*)&Bs[r][sg * 8] = ub.v;
        }
        __syncthreads();

        #pragma unroll
        for (int s = 0; s < 2; s++) {
            bf16x8 af[4], bfr[4];
            #pragma unroll
            for (int i = 0; i < 4; i++)
                af[i] = *(const bf16x8*)&As[wm * 64 + i * 16 + lrow][s * 32 + quad * 8];
            #pragma unroll
            for (int j = 0; j < 4; j++)
                bfr[j] = *(const bf16x8*)&Bs[wn * 64 + j * 16 + lrow][s * 32 + quad * 8];
            #pragma unroll
            for (int i = 0; i < 4; i++)
                #pragma unroll
                for (int j = 0; j < 4; j++)
                    acc[i][j] = __builtin_amdgcn_mfma_f32_16x16x32_bf16(
                        af[i], bfr[j], acc[i][j], 0, 0, 0);
        }
    }

    #pragma unroll
    for (int i = 0; i < 4; i++) {
        #pragma unroll
        for (int j = 0; j < 4; j++) {
            int col = ncol0 + wn * 64 + j * 16 + lrow;
            #pragma unroll
            for (int r = 0; r < 4; r++) {
                int gr = mrow0 + wm * 64 + i * 16 + quad * 4 + r;
                if (gr < N_NODES)
                    h[(size_t)gr * WIDTH + col] = __float2bfloat16(acc[i][j][r]);
            }
        }
    }
}

// ---------------------------------------------------------------------------
// Fused gather + self-loop + bias + LayerNorm + ReLU.
// One wave per dst node; lane l owns cols 4l..4l+3. Inner loop unrolled x4
// so 4 independent row loads are in flight (hide L2/HBM latency).
// ---------------------------------------------------------------------------
__global__ __launch_bounds__(256) void gather_ln(const __hip_bfloat16* __restrict__ h,
                                                 const float* __restrict__ dinv,
                                                 const int* __restrict__ offsets,
                                                 const int2* __restrict__ csr2,
                                                 const float* __restrict__ b,
                                                 const float* __restrict__ gamma,
                                                 const float* __restrict__ beta,
                                                 float* __restrict__ out) {
    const int lane = threadIdx.x & 63;
    const int d    = blockIdx.x * 4 + (threadIdx.x >> 6);

    const uint2* hrows = (const uint2*)h;        // 64 uint2 per row
    int beg = offsets[d], end = offsets[d + 1];
    float dv = dinv[d];

    uint2 hv = hrows[(size_t)d * 64 + lane];
    float a0 = dv * bf_lo(hv.x), a1 = dv * bf_hi(hv.x);
    float a2 = dv * bf_lo(hv.y), a3 = dv * bf_hi(hv.y);

    for (int base = beg; base < end; base += 64) {
        int cnt = min(end - base, 64);
        int   s  = 0;
        float sv = 0.0f;
        if (lane < cnt) {
            int2 p = csr2[base + lane];
            s  = p.x;
            sv = __int_as_float(p.y);
        }
        int q = 0;
        for (; q + 4 <= cnt; q += 4) {
            int   s0 = __shfl(s, q, 64),     s1 = __shfl(s, q + 1, 64);
            int   s2 = __shfl(s, q + 2, 64), s3 = __shfl(s, q + 3, 64);
            float w0 = __shfl(sv, q, 64),     w1 = __shfl(sv, q + 1, 64);
            float w2 = __shfl(sv, q + 2, 64), w3 = __shfl(sv, q + 3, 64);
            uint2 r0 = hrows[(size_t)s0 * 64 + lane];
            uint2 r1 = hrows[(size_t)s1 * 64 + lane];
            uint2 r2 = hrows[(size_t)s2 * 64 + lane];
            uint2 r3 = hrows[(size_t)s3 * 64 + lane];
            a0 += w0 * bf_lo(r0.x); a1 += w0 * bf_hi(r0.x);
            a2 += w0 * bf_lo(r0.y); a3 += w0 * bf_hi(r0.y);
            a0 += w1 * bf_lo(r1.x); a1 += w1 * bf_hi(r1.x);
            a2 += w1 * bf_lo(r1.y); a3 += w1 * bf_hi(r1.y);
            a0 += w2 * bf_lo(r2.x); a1 += w2 * bf_hi(r2.x);
            a2 += w2 * bf_lo(r2.y); a3 += w2 * bf_hi(r2.y);
            a0 += w3 * bf_lo(r3.x); a1 += w3 * bf_hi(r3.x);
            a2 += w3 * bf_lo(r3.y); a3 += w3 * bf_hi(r3.y);
        }
        for (; q < cnt; q++) {
            int   sq  = __shfl(s, q, 64);
            float svq = __shfl(sv, q, 64);
            uint2 rv  = hrows[(size_t)sq * 64 + lane];
            a0 += svq * bf_lo(rv.x);
            a1 += svq * bf_hi(rv.x);
            a2 += svq * bf_lo(rv.y);
            a3 += svq * bf_hi(rv.y);
        }
    }

    float4 bv = *(const float4*)(b + lane * 4);
    float v0 = bv.x + dv * a0;
    float v1 = bv.y + dv * a1;
    float v2 = bv.z + dv * a2;
    float v3 = bv.w + dv * a3;

    float s1 = v0 + v1 + v2 + v3;
    float s2 = v0 * v0 + v1 * v1 + v2 * v2 + v3 * v3;
    #pragma unroll
    for (int off = 32; off > 0; off >>= 1) {
        s1 += __shfl_xor(s1, off, 64);
        s2 += __shfl_xor(s2, off, 64);
    }
    float mu   = s1 * (1.0f / 256.0f);
    float var  = s2 * (1.0f / 256.0f) - mu * mu;
    float rstd = rsqrtf(var + LN_EPS);

    float4 gv = *(const float4*)(gamma + lane * 4);
    float4 bt = *(const float4*)(beta + lane * 4);
    float4 y;
    y.x = fmaxf((v0 - mu) * rstd * gv.x + bt.x, 0.0f);
    y.y = fmaxf((v1 - mu) * rstd * gv.y + bt.y, 0.0f);
    y.z = fmaxf((v2 - mu) * rstd * gv.z + bt.z, 0.0f);
    y.w = fmaxf((v3 - mu) * rstd * gv.w + bt.w, 0.0f);
    *(float4*)(out + (size_t)d * WIDTH + lane * 4) = y;
}

// ---------------------------------------------------------------------------
extern "C" void kernel_launch(void* const* d_in, const int* in_sizes, int n_in,
                              void* d_out, int out_size, void* d_ws, size_t ws_size,
                              hipStream_t stream) {
    const float* x     = (const float*)d_in[0];
    const int*   ei    = (const int*)d_in[1];   // [2, E] flat: src then dst
    const float* W     = (const float*)d_in[2];
    const float* b     = (const float*)d_in[3];
    const float* gamma = (const float*)d_in[4];
    const float* beta  = (const float*)d_in[5];
    float* out = (float*)d_out;

    const int* src = ei;
    const int* dst = ei + N_EDGES;

    const int n = N_NODES, e = N_EDGES;

    // workspace layout (4-byte word offsets):
    //   dinv    [0, 50048)
    //   h       [50048, 6450048)     bf16, 12.8M elems (6.4M words)
    //   counts  [6450048, 6500048)   -> cursor after scan
    //   offsets [6500048, 6550052)
    //   csr2    [6550080, 7175080)   int2 per edge (8B-aligned: word off even)
    float* wsf = (float*)d_ws;
    float*          dinv    = wsf;
    __hip_bfloat16* h       = (__hip_bfloat16*)(wsf + 50048);
    int*            counts  = (int*)(wsf + 6450048);
    int*            offsets = (int*)(wsf + 6500048);
    int2*           csr2    = (int2*)(wsf + 6550080);

    hipMemsetAsync(counts, 0, n * sizeof(int), stream);

    count_dst<<<(e + 255) / 256, 256, 0, stream>>>(dst, counts, e);
    scan_all <<<1, 1024, 0, stream>>>(counts, offsets, dinv);
    fill_csr <<<(e + 255) / 256, 256, 0, stream>>>(src, dst, dinv, counts, csr2, e);

    dim3 ggrid((N_NODES + 127) / 128, 2);
    gemm_mfma<<<ggrid, 256, 0, stream>>>(x, W, h);

    gather_ln<<<n / 4, 256, 0, stream>>>(h, dinv, offsets, csr2, b, gamma, beta, out);
}

// Round 6
// 205.764 us; speedup vs baseline: 1.4657x; 1.4657x over previous
//
#include <hip/hip_runtime.h>
#include <hip/hip_bf16.h>

#define N_NODES 50000
#define N_EDGES 312500
#define WIDTH   256
#define LN_EPS  1e-5f
#define NB_SCAN 196   // ceil(50000/256)

typedef __attribute__((ext_vector_type(8))) short bf16x8;
typedef __attribute__((ext_vector_type(4))) float f32x4;

__device__ __forceinline__ float bf_lo(unsigned u) { return __uint_as_float(u << 16); }
__device__ __forceinline__ float bf_hi(unsigned u) { return __uint_as_float(u & 0xffff0000u); }

// ---------------------------------------------------------------------------
// CSR build: count -> 3-pass parallel scan -> fill (packed with dinv[src])
// NOTE: single-block scan_all was tried in R4: 107us (one CU, 255 idle).
// The 3-pass 196-block scan totals ~6us. Keep it parallel.
// ---------------------------------------------------------------------------
__global__ void count_dst(const int* __restrict__ dst, int* __restrict__ counts, int e) {
    int i = blockIdx.x * blockDim.x + threadIdx.x;
    if (i < e) atomicAdd(&counts[dst[i]], 1);
}

__global__ __launch_bounds__(256) void scan_pass_a(const int* __restrict__ counts,
                                                   int* __restrict__ block_sums, int n) {
    int t = threadIdx.x;
    int i = blockIdx.x * 256 + t;
    int v = (i < n) ? counts[i] : 0;
    #pragma unroll
    for (int off = 32; off > 0; off >>= 1) v += __shfl_down(v, off, 64);
    __shared__ int ws[4];
    if ((t & 63) == 0) ws[t >> 6] = v;
    __syncthreads();
    if (t == 0) block_sums[blockIdx.x] = ws[0] + ws[1] + ws[2] + ws[3];
}

__global__ __launch_bounds__(256) void scan_pass_b(int* __restrict__ block_sums, int nb) {
    int t = threadIdx.x;
    int lane = t & 63, w = t >> 6;
    int v = (t < nb) ? block_sums[t] : 0;
    int inc = v;
    #pragma unroll
    for (int off = 1; off < 64; off <<= 1) {
        int u = __shfl_up(inc, off, 64);
        if (lane >= off) inc += u;
    }
    __shared__ int wsum[4];
    if (lane == 63) wsum[w] = inc;
    __syncthreads();
    int woff = 0;
    for (int k = 0; k < 4; k++) if (k < w) woff += wsum[k];
    if (t < nb) block_sums[t] = inc - v + woff;  // exclusive
}

__global__ __launch_bounds__(256) void scan_pass_c(int* __restrict__ counts,   // in: counts, out: cursor
                                                   const int* __restrict__ block_sums,
                                                   int* __restrict__ offsets,
                                                   float* __restrict__ dinv, int n) {
    int t = threadIdx.x;
    int i = blockIdx.x * 256 + t;
    int lane = t & 63, w = t >> 6;
    int v = (i < n) ? counts[i] : 0;
    int inc = v;
    #pragma unroll
    for (int off = 1; off < 64; off <<= 1) {
        int u = __shfl_up(inc, off, 64);
        if (lane >= off) inc += u;
    }
    __shared__ int wsum[4];
    if (lane == 63) wsum[w] = inc;
    __syncthreads();
    int woff = 0;
    for (int k = 0; k < 4; k++) if (k < w) woff += wsum[k];
    int excl = block_sums[blockIdx.x] + inc - v + woff;
    if (i < n) {
        offsets[i] = excl;
        counts[i]  = excl;                       // cursor starts at offset
        dinv[i]    = rsqrtf((float)(v + 1));     // +1 self-loop
    }
    if (i == n - 1) offsets[n] = N_EDGES;
}

// csr2[pos] = {src, bits(dinv[src])} -- kills the dependent dinv gather later
__global__ void fill_csr(const int* __restrict__ src, const int* __restrict__ dst,
                         const float* __restrict__ dinv,
                         int* __restrict__ cursor, int2* __restrict__ csr2, int e) {
    int i = blockIdx.x * blockDim.x + threadIdx.x;
    if (i < e) {
        int s = src[i];
        int pos = atomicAdd(&cursor[dst[i]], 1);
        csr2[pos] = make_int2(s, __float_as_int(dinv[s]));
    }
}

// ---------------------------------------------------------------------------
// MFMA GEMM with fused fp32->bf16 conversion in staging.
// h[m][nc] = sum_k x[m][k] * W[nc][k]; block 256 thr = 4 waves (2x2),
// tile 128x128, BK=64, K=256. LDS rows padded to 72 shorts.
// ---------------------------------------------------------------------------
__global__ __launch_bounds__(256) void gemm_mfma(const float* __restrict__ x,
                                                 const float* __restrict__ W,
                                                 __hip_bfloat16* __restrict__ h) {
    __shared__ short As[128][72];
    __shared__ short Bs[128][72];
    const int t    = threadIdx.x;
    const int lane = t & 63;
    const int wv   = t >> 6;
    const int wm   = wv & 1;
    const int wn   = wv >> 1;
    const int lrow = lane & 15;
    const int quad = lane >> 4;
    const int mrow0 = blockIdx.x * 128;
    const int ncol0 = blockIdx.y * 128;

    f32x4 acc[4][4];
    #pragma unroll
    for (int i = 0; i < 4; i++)
        #pragma unroll
        for (int j = 0; j < 4; j++)
            #pragma unroll
            for (int r = 0; r < 4; r++) acc[i][j][r] = 0.0f;

    const int sr = t >> 3;            // 0..31
    const int sg = t & 7;             // 0..7

    for (int kc = 0; kc < 4; kc++) {
        int k0 = kc * 64;
        if (kc) __syncthreads();
        #pragma unroll
        for (int p = 0; p < 4; p++) {
            int r  = p * 32 + sr;
            int gr = mrow0 + r;
            union { __hip_bfloat16 hh[8]; bf16x8 v; } ua;
            if (gr < N_NODES) {
                const float* xp = x + (size_t)gr * WIDTH + k0 + sg * 8;
                float4 f0 = *(const float4*)xp;
                float4 f1 = *(const float4*)(xp + 4);
                ua.hh[0] = __float2bfloat16(f0.x); ua.hh[1] = __float2bfloat16(f0.y);
                ua.hh[2] = __float2bfloat16(f0.z); ua.hh[3] = __float2bfloat16(f0.w);
                ua.hh[4] = __float2bfloat16(f1.x); ua.hh[5] = __float2bfloat16(f1.y);
                ua.hh[6] = __float2bfloat16(f1.z); ua.hh[7] = __float2bfloat16(f1.w);
            } else {
                ua.v = (bf16x8){0,0,0,0,0,0,0,0};
            }
            *(bf16x8*)&As[r][sg * 8] = ua.v;

            int gn = ncol0 + r;       // always < 256
            const float* wp = W + (size_t)gn * WIDTH + k0 + sg * 8;
            float4 g0 = *(const float4*)wp;
            float4 g1 = *(const float4*)(wp + 4);
            union { __hip_bfloat16 hh[8]; bf16x8 v; } ub;
            ub.hh[0] = __float2bfloat16(g0.x); ub.hh[1] = __float2bfloat16(g0.y);
            ub.hh[2] = __float2bfloat16(g0.z); ub.hh[3] = __float2bfloat16(g0.w);
            ub.hh[4] = __float2bfloat16(g1.x); ub.hh[5] = __float2bfloat16(g1.y);
            ub.hh[6] = __float2bfloat16(g1.z); ub.hh[7] = __float2bfloat16(g1.w);
            *(bf16x8*)&Bs[r][sg * 8] = ub.v;
        }
        __syncthreads();

        #pragma unroll
        for (int s = 0; s < 2; s++) {
            bf16x8 af[4], bfr[4];
            #pragma unroll
            for (int i = 0; i < 4; i++)
                af[i] = *(const bf16x8*)&As[wm * 64 + i * 16 + lrow][s * 32 + quad * 8];
            #pragma unroll
            for (int j = 0; j < 4; j++)
                bfr[j] = *(const bf16x8*)&Bs[wn * 64 + j * 16 + lrow][s * 32 + quad * 8];
            #pragma unroll
            for (int i = 0; i < 4; i++)
                #pragma unroll
                for (int j = 0; j < 4; j++)
                    acc[i][j] = __builtin_amdgcn_mfma_f32_16x16x32_bf16(
                        af[i], bfr[j], acc[i][j], 0, 0, 0);
        }
    }

    #pragma unroll
    for (int i = 0; i < 4; i++) {
        #pragma unroll
        for (int j = 0; j < 4; j++) {
            int col = ncol0 + wn * 64 + j * 16 + lrow;
            #pragma unroll
            for (int r = 0; r < 4; r++) {
                int gr = mrow0 + wm * 64 + i * 16 + quad * 4 + r;
                if (gr < N_NODES)
                    h[(size_t)gr * WIDTH + col] = __float2bfloat16(acc[i][j][r]);
            }
        }
    }
}

// ---------------------------------------------------------------------------
// Fused gather + self-loop + bias + LayerNorm + ReLU.
// One wave per dst node; lane l owns cols 4l..4l+3. Inner loop unrolled x4
// so 4 independent row loads are in flight (hide L2/HBM latency).
// ---------------------------------------------------------------------------
__global__ __launch_bounds__(256) void gather_ln(const __hip_bfloat16* __restrict__ h,
                                                 const float* __restrict__ dinv,
                                                 const int* __restrict__ offsets,
                                                 const int2* __restrict__ csr2,
                                                 const float* __restrict__ b,
                                                 const float* __restrict__ gamma,
                                                 const float* __restrict__ beta,
                                                 float* __restrict__ out) {
    const int lane = threadIdx.x & 63;
    const int d    = blockIdx.x * 4 + (threadIdx.x >> 6);

    const uint2* hrows = (const uint2*)h;        // 64 uint2 per row
    int beg = offsets[d], end = offsets[d + 1];
    float dv = dinv[d];

    uint2 hv = hrows[(size_t)d * 64 + lane];
    float a0 = dv * bf_lo(hv.x), a1 = dv * bf_hi(hv.x);
    float a2 = dv * bf_lo(hv.y), a3 = dv * bf_hi(hv.y);

    for (int base = beg; base < end; base += 64) {
        int cnt = min(end - base, 64);
        int   s  = 0;
        float sv = 0.0f;
        if (lane < cnt) {
            int2 p = csr2[base + lane];
            s  = p.x;
            sv = __int_as_float(p.y);
        }
        int q = 0;
        for (; q + 4 <= cnt; q += 4) {
            int   s0 = __shfl(s, q, 64),     s1 = __shfl(s, q + 1, 64);
            int   s2 = __shfl(s, q + 2, 64), s3 = __shfl(s, q + 3, 64);
            float w0 = __shfl(sv, q, 64),     w1 = __shfl(sv, q + 1, 64);
            float w2 = __shfl(sv, q + 2, 64), w3 = __shfl(sv, q + 3, 64);
            uint2 r0 = hrows[(size_t)s0 * 64 + lane];
            uint2 r1 = hrows[(size_t)s1 * 64 + lane];
            uint2 r2 = hrows[(size_t)s2 * 64 + lane];
            uint2 r3 = hrows[(size_t)s3 * 64 + lane];
            a0 += w0 * bf_lo(r0.x); a1 += w0 * bf_hi(r0.x);
            a2 += w0 * bf_lo(r0.y); a3 += w0 * bf_hi(r0.y);
            a0 += w1 * bf_lo(r1.x); a1 += w1 * bf_hi(r1.x);
            a2 += w1 * bf_lo(r1.y); a3 += w1 * bf_hi(r1.y);
            a0 += w2 * bf_lo(r2.x); a1 += w2 * bf_hi(r2.x);
            a2 += w2 * bf_lo(r2.y); a3 += w2 * bf_hi(r2.y);
            a0 += w3 * bf_lo(r3.x); a1 += w3 * bf_hi(r3.x);
            a2 += w3 * bf_lo(r3.y); a3 += w3 * bf_hi(r3.y);
        }
        for (; q < cnt; q++) {
            int   sq  = __shfl(s, q, 64);
            float svq = __shfl(sv, q, 64);
            uint2 rv  = hrows[(size_t)sq * 64 + lane];
            a0 += svq * bf_lo(rv.x);
            a1 += svq * bf_hi(rv.x);
            a2 += svq * bf_lo(rv.y);
            a3 += svq * bf_hi(rv.y);
        }
    }

    float4 bv = *(const float4*)(b + lane * 4);
    float v0 = bv.x + dv * a0;
    float v1 = bv.y + dv * a1;
    float v2 = bv.z + dv * a2;
    float v3 = bv.w + dv * a3;

    float s1 = v0 + v1 + v2 + v3;
    float s2 = v0 * v0 + v1 * v1 + v2 * v2 + v3 * v3;
    #pragma unroll
    for (int off = 32; off > 0; off >>= 1) {
        s1 += __shfl_xor(s1, off, 64);
        s2 += __shfl_xor(s2, off, 64);
    }
    float mu   = s1 * (1.0f / 256.0f);
    float var  = s2 * (1.0f / 256.0f) - mu * mu;
    float rstd = rsqrtf(var + LN_EPS);

    float4 gv = *(const float4*)(gamma + lane * 4);
    float4 bt = *(const float4*)(beta + lane * 4);
    float4 y;
    y.x = fmaxf((v0 - mu) * rstd * gv.x + bt.x, 0.0f);
    y.y = fmaxf((v1 - mu) * rstd * gv.y + bt.y, 0.0f);
    y.z = fmaxf((v2 - mu) * rstd * gv.z + bt.z, 0.0f);
    y.w = fmaxf((v3 - mu) * rstd * gv.w + bt.w, 0.0f);
    *(float4*)(out + (size_t)d * WIDTH + lane * 4) = y;
}

// ---------------------------------------------------------------------------
extern "C" void kernel_launch(void* const* d_in, const int* in_sizes, int n_in,
                              void* d_out, int out_size, void* d_ws, size_t ws_size,
                              hipStream_t stream) {
    const float* x     = (const float*)d_in[0];
    const int*   ei    = (const int*)d_in[1];   // [2, E] flat: src then dst
    const float* W     = (const float*)d_in[2];
    const float* b     = (const float*)d_in[3];
    const float* gamma = (const float*)d_in[4];
    const float* beta  = (const float*)d_in[5];
    float* out = (float*)d_out;

    const int* src = ei;
    const int* dst = ei + N_EDGES;

    const int n = N_NODES, e = N_EDGES;

    // workspace layout (4-byte word offsets):
    //   dinv    [0, 50048)
    //   h       [50048, 6450048)     bf16, 12.8M elems (6.4M words)
    //   counts  [6450048, 6500048)   -> cursor after scan
    //   offsets [6500048, 6550052)
    //   bsums   [6550052, 6550308)
    //   csr2    [6550308->6550310 pad, 6550310..]  int2 per edge, 8B aligned
    float* wsf = (float*)d_ws;
    float*          dinv       = wsf;
    __hip_bfloat16* h          = (__hip_bfloat16*)(wsf + 50048);
    int*            counts     = (int*)(wsf + 6450048);
    int*            offsets    = (int*)(wsf + 6500048);
    int*            block_sums = (int*)(wsf + 6550052);
    int2*           csr2       = (int2*)(wsf + 6550310);  // even word offset -> 8B aligned

    hipMemsetAsync(counts, 0, n * sizeof(int), stream);

    count_dst  <<<(e + 255) / 256, 256, 0, stream>>>(dst, counts, e);
    scan_pass_a<<<NB_SCAN, 256, 0, stream>>>(counts, block_sums, n);
    scan_pass_b<<<1, 256, 0, stream>>>(block_sums, NB_SCAN);
    scan_pass_c<<<NB_SCAN, 256, 0, stream>>>(counts, block_sums, offsets, dinv, n);
    fill_csr   <<<(e + 255) / 256, 256, 0, stream>>>(src, dst, dinv, counts, csr2, e);

    dim3 ggrid((N_NODES + 127) / 128, 2);
    gemm_mfma<<<ggrid, 256, 0, stream>>>(x, W, h);

    gather_ln<<<n / 4, 256, 0, stream>>>(h, dinv, offsets, csr2, b, gamma, beta, out);
}